// Round 5
// baseline (12.133 us; speedup 1.0000x reference)
//
#include <hip/hip_runtime.h>

// QuantumKernelAttention, rank-16 factorization + MFMA epilogue (R8):
//   K[b,i,j] = prod_k ( c_ik c_jk + s_ik s_jk ) = sum_t F[i,t] F[j,t]  (rank 16)
//   Gram tile via v_mfma_f32_32x32x16_f16. E = exp(|K|) is computed WITHOUT the
//   trans pipe: 8x v_cvt_pkrtz (|.| folded into src mods) pack |K| pairs to f16,
//   then a degree-4 Horner in packed f16 (v_pk_fma_f16, 2 lanes/op) evaluates
//   e^t, t in [0,1] (Chebyshev coeffs, poly err <= 3e-5). Output absmax is
//   dominated by X's f16 quantization (~1 ulp = 0.002); E-side poly/f16 error
//   cancels in the softmax ratio (delta_w ~ delta_e / sum_e, sum_e ~ 1700).
//   The poly result IS the packed f16 E-fragment: permlane32_swap builds the
//   32x32x16 A-fragments, second MFMA vs [x | 1]^T gives sum(e*x) and sum(e).
// R8 vs R7: main loop trans count 16/tile -> 0 (trans was the largest pipe
// consumer, and barrier-phased waves hit the exp burst in convoy, so trans
// time summed across the 4 waves/SIMD instead of overlapping). F pre-scale
// removed (poly takes |K| directly). Everything else identical to R7.

typedef _Float16 f16x8 __attribute__((ext_vector_type(8)));
typedef _Float16 h2    __attribute__((ext_vector_type(2)));
typedef float    f32x16 __attribute__((ext_vector_type(16)));
typedef unsigned int u32x4 __attribute__((ext_vector_type(4)));

#define SQ 1024
#define NTHREADS 512   // 8 waves: 2 row-tiles x 4 j-quarters
#define ROWS 64        // output rows per block

#if __has_builtin(__builtin_amdgcn_permlane32_swap)
__device__ __forceinline__ void pl32swap(unsigned &a, unsigned &b) {
    auto r = __builtin_amdgcn_permlane32_swap(a, b, false, false);
    a = r[0]; b = r[1];
}
#else
__device__ __forceinline__ void pl32swap(unsigned &a, unsigned &b) {
    asm("v_permlane32_swap_b32 %0, %1" : "+v"(a), "+v"(b));
}
#endif

// e^|.| for a pair of f32, evaluated in packed f16 (no trans pipe).
// Deg-4 Chebyshev-derived Horner on [0,1]: max poly err ~3e-5 on e^t.
__device__ __forceinline__ unsigned pexp_abs(float a, float b) {
    auto tp = __builtin_amdgcn_cvt_pkrtz(fabsf(a), fabsf(b)); // abs -> src mods
    h2 t = __builtin_bit_cast(h2, tp);
    const h2 C4 = {(_Float16)0.0695580f, (_Float16)0.0695580f};
    const h2 C3 = {(_Float16)0.1399810f, (_Float16)0.1399810f};
    const h2 C2 = {(_Float16)0.5100530f, (_Float16)0.5100530f};
    const h2 C1 = {(_Float16)0.9986730f, (_Float16)0.9986730f};
    const h2 C0 = {(_Float16)0.9999940f, (_Float16)0.9999940f};
    h2 p = __builtin_elementwise_fma(C4, t, C3);
    p = __builtin_elementwise_fma(p, t, C2);
    p = __builtin_elementwise_fma(p, t, C1);
    p = __builtin_elementwise_fma(p, t, C0);
    return __builtin_bit_cast(unsigned, p);
}

__global__ __launch_bounds__(NTHREADS, 4)
void qka_kernel(const float* __restrict__ x, float* __restrict__ out) {
    // F factors, k-halves split; rows XOR-swizzled (j ^ ((j>>3)&7)) so a wave's
    // ds_read_b128 of 32 consecutive rows is conflict-minimal.
    __shared__ f16x8 lds_F0[SQ];        // 16 KB  F[j][k=0..7]
    __shared__ f16x8 lds_F1[SQ];        // 16 KB  F[j][k=8..15]
    // X^T extended, f16: rows 0..3 = x components, row 4 = ones (denominator).
    __shared__ f16x8 lds_XT[5 * 129];   // ~10.1 KB, pitch 129 f16x8

    const int bid   = blockIdx.x;
    const int b     = bid >> 4;          // 16 row-tiles (of 64) per batch
    const int Ibase = (bid & 15) * ROWS;
    const int tid   = threadIdx.x;

    const float4* xb  = (const float4*)(x + (size_t)b * SQ * 4);
    _Float16*     xtp = (_Float16*)lds_XT;

    // ---- stage: F (f16, swizzled) and X^T+ones (f16), whole batch ----
    #pragma unroll
    for (int k = 0; k < SQ / NTHREADS; ++k) {
        int j = tid + k * NTHREADS;
        float4 v = xb[j];
        float c0 = __cosf(0.5f * v.x), s0 = __sinf(0.5f * v.x);
        float c1 = __cosf(0.5f * v.y), s1 = __sinf(0.5f * v.y);
        float c2 = __cosf(0.5f * v.z), s2 = __sinf(0.5f * v.z);
        float c3 = __cosf(0.5f * v.w), s3 = __sinf(0.5f * v.w);
        float m0 = c0 * c1, m1 = s0 * c1, m2 = c0 * s1, m3 = s0 * s1;
        float n0 = m0 * c2, n1 = m1 * c2, n2 = m2 * c2, n3 = m3 * c2;
        float n4 = m0 * s2, n5 = m1 * s2, n6 = m2 * s2, n7 = m3 * s2;
        f16x8 p0, p1;
        p0[0] = (_Float16)(n0 * c3); p0[1] = (_Float16)(n1 * c3);
        p0[2] = (_Float16)(n2 * c3); p0[3] = (_Float16)(n3 * c3);
        p0[4] = (_Float16)(n4 * c3); p0[5] = (_Float16)(n5 * c3);
        p0[6] = (_Float16)(n6 * c3); p0[7] = (_Float16)(n7 * c3);
        p1[0] = (_Float16)(n0 * s3); p1[1] = (_Float16)(n1 * s3);
        p1[2] = (_Float16)(n2 * s3); p1[3] = (_Float16)(n3 * s3);
        p1[4] = (_Float16)(n4 * s3); p1[5] = (_Float16)(n5 * s3);
        p1[6] = (_Float16)(n6 * s3); p1[7] = (_Float16)(n7 * s3);
        int sj = j ^ ((j >> 3) & 7);
        lds_F0[sj] = p0;
        lds_F1[sj] = p1;
        xtp[0 * 1032 + j] = (_Float16)v.x;
        xtp[1 * 1032 + j] = (_Float16)v.y;
        xtp[2 * 1032 + j] = (_Float16)v.z;
        xtp[3 * 1032 + j] = (_Float16)v.w;
        xtp[4 * 1032 + j] = (_Float16)1.0f;
    }
    __syncthreads();

    // ---- main: wave = (row-tile rt, j-quarter q); 8 tiles of 32 j each ----
    const int wid  = tid >> 6;
    const int q    = wid & 3;            // j-quarter: j in [256q, 256q+256)
    const int rt   = wid >> 2;           // row-tile within block (0/1)
    const int lane = tid & 63;
    const int h    = lane >> 5;          // k-half selector
    const int ln   = lane & 31;

    const f16x8* Fh = h ? lds_F1 : lds_F0;
    int ib = Ibase + rt * 32 + ln; ib ^= (ib >> 3) & 7;
    const f16x8 bfrag = Fh[ib];          // B: F[I-tile] rows (col n = i)

    // PV B-frag: lane col n reads X^T row min(n,4); cols >=5 never read back.
    const int rowsel = (ln < 4) ? ln : 4;
    const int xbase  = rowsel * 129 + q * 32 + h;   // f16x8 index

    f32x16 oacc0 = (f32x16)(0.0f);       // e-rows k=j' 0..15
    f32x16 oacc1 = (f32x16)(0.0f);       // e-rows k=j' 16..31

    // Gram for tile 0, pipelined one tile ahead of the poly/PV stage.
    int ja0 = q * 256 + ln;
    f16x8 af0 = Fh[ja0 ^ ((ja0 >> 3) & 7)];
    f32x16 d = __builtin_amdgcn_mfma_f32_32x32x16_f16(
        af0, bfrag, (f32x16)(0.0f), 0, 0, 0);

    #pragma unroll 2
    for (int t = 0; t < 8; ++t) {
        // Issue this iteration's LDS reads first (latency hidden under poly).
        f16x8 afn;
        if (t < 7) {
            int jn = q * 256 + (t + 1) * 32 + ln;
            afn = Fh[jn ^ ((jn >> 3) & 7)];
        }
        f16x8 xf0 = lds_XT[xbase + t * 4];        // X rows [jb, jb+16)
        f16x8 xf1 = lds_XT[xbase + t * 4 + 2];    // X rows [jb+16, jb+32)
        // d[r] = K[j', i], j' = (r&3)+8(r>>2)+4h; e = poly(|d|) in packed f16.
        unsigned q0 = pexp_abs(d[0],  d[1]);
        unsigned q1 = pexp_abs(d[2],  d[3]);
        unsigned q2 = pexp_abs(d[4],  d[5]);
        unsigned q3 = pexp_abs(d[6],  d[7]);
        unsigned q4 = pexp_abs(d[8],  d[9]);
        unsigned q5 = pexp_abs(d[10], d[11]);
        unsigned q6 = pexp_abs(d[12], d[13]);
        unsigned q7 = pexp_abs(d[14], d[15]);
        // Gram for tile t+1; d is dead (consumed above), dn reuses its regs.
        f32x16 dn;
        if (t < 7)
            dn = __builtin_amdgcn_mfma_f32_32x32x16_f16(
                afn, bfrag, (f32x16)(0.0f), 0, 0, 0);
        pl32swap(q0, q2); pl32swap(q1, q3);   // frag0 dwords 0..3 (k = 0..15)
        pl32swap(q4, q6); pl32swap(q5, q7);   // frag1 dwords 0..3 (k = 16..31)
        u32x4 w0 = {q0, q1, q2, q3};
        u32x4 w1 = {q4, q5, q6, q7};
        f16x8 ef0 = __builtin_bit_cast(f16x8, w0);
        f16x8 ef1 = __builtin_bit_cast(f16x8, w1);
        oacc0 = __builtin_amdgcn_mfma_f32_32x32x16_f16(ef0, xf0, oacc0, 0, 0, 0);
        oacc1 = __builtin_amdgcn_mfma_f32_32x32x16_f16(ef1, xf1, oacc1, 0, 0, 0);
        if (t < 7) d = dn;
    }

    // ---- cross-wave combine: partials in LDS (alias onto lds_F0, now dead) ----
    __syncthreads();                     // all waves done reading F / XT
    float* ps = (float*)lds_F0;          // [q=4][64 rows][8 cols f32] = 8 KB
    if (ln < 5) {                        // cols 0..4 valid, both halves
        #pragma unroll
        for (int r = 0; r < 16; ++r) {
            int m = (r & 3) + 8 * (r >> 2) + 4 * h;   // row within 32-tile
            ps[(q * 64 + rt * 32 + m) * 8 + ln] = oacc0[r] + oacc1[r];
        }
    }
    __syncthreads();

    if (tid < ROWS) {
        float nx = 0.f, ny = 0.f, nz = 0.f, nw = 0.f, den = 0.f;
        #pragma unroll
        for (int qq = 0; qq < 4; ++qq) {
            const float* p = &ps[(qq * 64 + tid) * 8];
            nx += p[0]; ny += p[1]; nz += p[2]; nw += p[3]; den += p[4];
        }
        float inv = 1.0f / den;
        ((float4*)out)[(size_t)b * SQ + Ibase + tid] =
            make_float4(nx * inv, ny * inv, nz * inv, nw * inv);
    }
}

extern "C" void kernel_launch(void* const* d_in, const int* in_sizes, int n_in,
                              void* d_out, int out_size, void* d_ws, size_t ws_size,
                              hipStream_t stream) {
    const float* x = (const float*)d_in[0];
    float* out = (float*)d_out;
    dim3 grid(32 * (SQ / ROWS));   // 512 blocks
    dim3 block(NTHREADS);
    qka_kernel<<<grid, block, 0, stream>>>(x, out);
}